// Round 8
// baseline (353.663 us; speedup 1.0000x reference)
//
#include <hip/hip_runtime.h>
#include <hip/hip_bf16.h>

// Problem constants
#define DMODEL 1024
#define DIN    2048
#define NH     32
#define HD     64
#define DS     64
#define LSEQ   1024
#define BB     2
#define DTOT   5312           // 2*DIN + 2*64 + 32 + 1024 + 32
#define ROWS   (BB*LSEQ)      // 2048
// column offsets inside zxbcdt
#define OFF_Z   0
#define OFF_X   2048
#define OFF_BR  4096
#define OFF_CR  4160
#define OFF_DT  4224
#define OFF_TH  4256
#define OFF_LAM 5280
#define NZX     4096          // z+x columns done in single-pass bf16 MFMA
#define NREM    (DTOT - NZX)  // 1216 cols done in 3-pass split-bf16 MFMA

typedef short  s16x8 __attribute__((ext_vector_type(8)));
typedef float  f32x4 __attribute__((ext_vector_type(4)));

__device__ __forceinline__ unsigned int f2bf(float f) {   // RNE f32->bf16 (finite inputs)
    unsigned int u = __float_as_uint(f);
    u += 0x7fffu + ((u >> 16) & 1u);
    return u >> 16;
}
// pack two floats to bf16x2
__device__ __forceinline__ unsigned int pk(float x, float y) {
    return f2bf(x) | (f2bf(y) << 16);
}
// split two floats into bf16x2 hi + bf16x2 lo (residual)
__device__ __forceinline__ void split2(float x, float y, unsigned int& h, unsigned int& l) {
    const unsigned int hx = f2bf(x), hy = f2bf(y);
    h = hx | (hy << 16);
    l = pk(x - __uint_as_float(hx << 16), y - __uint_as_float(hy << 16));
}

// ---------------------------------------------------------------------------
// bf16 MFMA GEMM, z/x block: zx[:, 0:4096] = u @ W[0:4096,:]^T
// 128x128 tile, BK=32, 4 waves (2x2), wave = 64x64 out.
// ---------------------------------------------------------------------------
#define LDB 40
__global__ __launch_bounds__(256) void mfma_gemm_zx(const float* __restrict__ u,
                                                    const float* __restrict__ W,
                                                    float* __restrict__ zx) {
    __shared__ unsigned short Al[128][LDB];
    __shared__ unsigned short Bl[128][LDB];
    const int tid = threadIdx.x;
    const int m0 = blockIdx.y * 128, n0 = blockIdx.x * 128;
    const int lane = tid & 63, wave = tid >> 6;
    const int wr = wave >> 1, wc = wave & 1;
    const int lr = lane >> 4, lc = lane & 15;
    const int r  = tid >> 2;
    const int cb = (tid & 3) * 8;

    f32x4 acc[4][4] = {};

    const float* uA = u + (size_t)(m0 + r) * DMODEL + cb;
    const float* uB = W + (size_t)(n0 + r) * DMODEL + cb;

    for (int k0 = 0; k0 < DMODEL; k0 += 32) {
        const float4 a0 = *(const float4*)(uA + k0);
        const float4 a1 = *(const float4*)(uA + k0 + 4);
        const float4 a2 = *(const float4*)(uA + k0 + (size_t)64 * DMODEL);
        const float4 a3 = *(const float4*)(uA + k0 + (size_t)64 * DMODEL + 4);
        const float4 b0 = *(const float4*)(uB + k0);
        const float4 b1 = *(const float4*)(uB + k0 + 4);
        const float4 b2 = *(const float4*)(uB + k0 + (size_t)64 * DMODEL);
        const float4 b3 = *(const float4*)(uB + k0 + (size_t)64 * DMODEL + 4);
        __syncthreads();
        uint4 q;
        q.x = pk(a0.x, a0.y); q.y = pk(a0.z, a0.w); q.z = pk(a1.x, a1.y); q.w = pk(a1.z, a1.w);
        *(uint4*)&Al[r][cb] = q;
        q.x = pk(a2.x, a2.y); q.y = pk(a2.z, a2.w); q.z = pk(a3.x, a3.y); q.w = pk(a3.z, a3.w);
        *(uint4*)&Al[r + 64][cb] = q;
        q.x = pk(b0.x, b0.y); q.y = pk(b0.z, b0.w); q.z = pk(b1.x, b1.y); q.w = pk(b1.z, b1.w);
        *(uint4*)&Bl[r][cb] = q;
        q.x = pk(b2.x, b2.y); q.y = pk(b2.z, b2.w); q.z = pk(b3.x, b3.y); q.w = pk(b3.z, b3.w);
        *(uint4*)&Bl[r + 64][cb] = q;
        __syncthreads();
        s16x8 af[4], bf[4];
        #pragma unroll
        for (int f = 0; f < 4; ++f) {
            af[f] = *(const s16x8*)&Al[wr * 64 + f * 16 + lc][lr * 8];
            bf[f] = *(const s16x8*)&Bl[wc * 64 + f * 16 + lc][lr * 8];
        }
        #pragma unroll
        for (int fm = 0; fm < 4; ++fm)
            #pragma unroll
            for (int fn = 0; fn < 4; ++fn)
                acc[fm][fn] = __builtin_amdgcn_mfma_f32_16x16x32_bf16(
                    af[fm], bf[fn], acc[fm][fn], 0, 0, 0);
    }

    #pragma unroll
    for (int fm = 0; fm < 4; ++fm)
        #pragma unroll
        for (int fn = 0; fn < 4; ++fn) {
            const size_t col = n0 + wc * 64 + fn * 16 + lc;
            #pragma unroll
            for (int j = 0; j < 4; ++j) {
                const size_t row = m0 + wr * 64 + fm * 16 + lr * 4 + j;
                zx[row * DTOT + col] = acc[fm][fn][j];
            }
        }
}

// ---------------------------------------------------------------------------
// bf16 MFMA GEMM, generic 128x64 tile single-pass: C = A[M][K] @ B[N][K]^T
// 4 waves (2x2), wave = 64x32 out. Used for out_proj (N=1024, K=2048).
// ---------------------------------------------------------------------------
__global__ __launch_bounds__(256) void mfma_gemm_out(const float* __restrict__ A,
                                                     const float* __restrict__ B,
                                                     float* __restrict__ C,
                                                     int K, int ldc) {
    __shared__ unsigned short Als[128][LDB];
    __shared__ unsigned short Bls[64][LDB];
    const int tid = threadIdx.x;
    const int m0 = blockIdx.y * 128, n0 = blockIdx.x * 64;
    const int lane = tid & 63, wave = tid >> 6;
    const int wr = wave >> 1, wc = wave & 1;
    const int lr = lane >> 4, lc = lane & 15;
    const int r  = tid >> 2;
    const int cb = (tid & 3) * 8;

    f32x4 acc[4][2] = {};

    const float* pA = A + (size_t)(m0 + r) * K + cb;
    const float* pB = B + (size_t)(n0 + r) * K + cb;

    for (int k0 = 0; k0 < K; k0 += 32) {
        const float4 a0 = *(const float4*)(pA + k0);
        const float4 a1 = *(const float4*)(pA + k0 + 4);
        const float4 a2 = *(const float4*)(pA + k0 + (size_t)64 * K);
        const float4 a3 = *(const float4*)(pA + k0 + (size_t)64 * K + 4);
        const float4 b0 = *(const float4*)(pB + k0);
        const float4 b1 = *(const float4*)(pB + k0 + 4);
        __syncthreads();
        uint4 q;
        q.x = pk(a0.x, a0.y); q.y = pk(a0.z, a0.w); q.z = pk(a1.x, a1.y); q.w = pk(a1.z, a1.w);
        *(uint4*)&Als[r][cb] = q;
        q.x = pk(a2.x, a2.y); q.y = pk(a2.z, a2.w); q.z = pk(a3.x, a3.y); q.w = pk(a3.z, a3.w);
        *(uint4*)&Als[r + 64][cb] = q;
        q.x = pk(b0.x, b0.y); q.y = pk(b0.z, b0.w); q.z = pk(b1.x, b1.y); q.w = pk(b1.z, b1.w);
        *(uint4*)&Bls[r][cb] = q;
        __syncthreads();
        s16x8 af[4], bf[2];
        #pragma unroll
        for (int f = 0; f < 4; ++f)
            af[f] = *(const s16x8*)&Als[wr * 64 + f * 16 + lc][lr * 8];
        #pragma unroll
        for (int f = 0; f < 2; ++f)
            bf[f] = *(const s16x8*)&Bls[wc * 32 + f * 16 + lc][lr * 8];
        #pragma unroll
        for (int fm = 0; fm < 4; ++fm)
            #pragma unroll
            for (int fn = 0; fn < 2; ++fn)
                acc[fm][fn] = __builtin_amdgcn_mfma_f32_16x16x32_bf16(
                    af[fm], bf[fn], acc[fm][fn], 0, 0, 0);
    }

    #pragma unroll
    for (int fm = 0; fm < 4; ++fm)
        #pragma unroll
        for (int fn = 0; fn < 2; ++fn) {
            const size_t col = n0 + wc * 32 + fn * 16 + lc;
            #pragma unroll
            for (int j = 0; j < 4; ++j) {
                const size_t row = m0 + wr * 64 + fm * 16 + lr * 4 + j;
                C[row * (size_t)ldc + col] = acc[fm][fn][j];
            }
        }
}

// ---------------------------------------------------------------------------
// split-bf16 3-pass MFMA GEMM for the sensitive columns (theta cumsum!):
// u=uh+ul, W=wh+wl; acc += uh*wh + uh*wl + ul*wh  (~fp32 accuracy, MFMA speed)
// 128x64 tile, N=1216=19*64 exact. ldc=DTOT, out offset +NZX by caller.
// ---------------------------------------------------------------------------
__global__ __launch_bounds__(256) void mfma_gemm_rem3(const float* __restrict__ u,
                                                      const float* __restrict__ W,
                                                      float* __restrict__ zxr) {
    __shared__ unsigned short Ah[128][LDB], Alo[128][LDB];
    __shared__ unsigned short Bh[64][LDB],  Blo[64][LDB];
    const int tid = threadIdx.x;
    const int m0 = blockIdx.y * 128, n0 = blockIdx.x * 64;
    const int lane = tid & 63, wave = tid >> 6;
    const int wr = wave >> 1, wc = wave & 1;
    const int lr = lane >> 4, lc = lane & 15;
    const int r  = tid >> 2;
    const int cb = (tid & 3) * 8;

    f32x4 acc[4][2] = {};

    const float* pA = u + (size_t)(m0 + r) * DMODEL + cb;
    const float* pB = W + (size_t)(n0 + r) * DMODEL + cb;   // n0+r <= 1215 < NREM

    for (int k0 = 0; k0 < DMODEL; k0 += 32) {
        const float4 a0 = *(const float4*)(pA + k0);
        const float4 a1 = *(const float4*)(pA + k0 + 4);
        const float4 a2 = *(const float4*)(pA + k0 + (size_t)64 * DMODEL);
        const float4 a3 = *(const float4*)(pA + k0 + (size_t)64 * DMODEL + 4);
        const float4 b0 = *(const float4*)(pB + k0);
        const float4 b1 = *(const float4*)(pB + k0 + 4);
        __syncthreads();
        uint4 qh, ql;
        split2(a0.x, a0.y, qh.x, ql.x); split2(a0.z, a0.w, qh.y, ql.y);
        split2(a1.x, a1.y, qh.z, ql.z); split2(a1.z, a1.w, qh.w, ql.w);
        *(uint4*)&Ah[r][cb] = qh; *(uint4*)&Alo[r][cb] = ql;
        split2(a2.x, a2.y, qh.x, ql.x); split2(a2.z, a2.w, qh.y, ql.y);
        split2(a3.x, a3.y, qh.z, ql.z); split2(a3.z, a3.w, qh.w, ql.w);
        *(uint4*)&Ah[r + 64][cb] = qh; *(uint4*)&Alo[r + 64][cb] = ql;
        split2(b0.x, b0.y, qh.x, ql.x); split2(b0.z, b0.w, qh.y, ql.y);
        split2(b1.x, b1.y, qh.z, ql.z); split2(b1.z, b1.w, qh.w, ql.w);
        *(uint4*)&Bh[r][cb] = qh; *(uint4*)&Blo[r][cb] = ql;
        __syncthreads();
        s16x8 ahf[4], alf[4], bhf[2], blf[2];
        #pragma unroll
        for (int f = 0; f < 4; ++f) {
            ahf[f] = *(const s16x8*)&Ah[wr * 64 + f * 16 + lc][lr * 8];
            alf[f] = *(const s16x8*)&Alo[wr * 64 + f * 16 + lc][lr * 8];
        }
        #pragma unroll
        for (int f = 0; f < 2; ++f) {
            bhf[f] = *(const s16x8*)&Bh[wc * 32 + f * 16 + lc][lr * 8];
            blf[f] = *(const s16x8*)&Blo[wc * 32 + f * 16 + lc][lr * 8];
        }
        #pragma unroll
        for (int fm = 0; fm < 4; ++fm)
            #pragma unroll
            for (int fn = 0; fn < 2; ++fn) {
                acc[fm][fn] = __builtin_amdgcn_mfma_f32_16x16x32_bf16(
                    ahf[fm], bhf[fn], acc[fm][fn], 0, 0, 0);
                acc[fm][fn] = __builtin_amdgcn_mfma_f32_16x16x32_bf16(
                    ahf[fm], blf[fn], acc[fm][fn], 0, 0, 0);
                acc[fm][fn] = __builtin_amdgcn_mfma_f32_16x16x32_bf16(
                    alf[fm], bhf[fn], acc[fm][fn], 0, 0, 0);
            }
    }

    #pragma unroll
    for (int fm = 0; fm < 4; ++fm)
        #pragma unroll
        for (int fn = 0; fn < 2; ++fn) {
            const size_t col = n0 + wc * 32 + fn * 16 + lc;
            #pragma unroll
            for (int j = 0; j < 4; ++j) {
                const size_t row = m0 + wr * 64 + fm * 16 + lr * 4 + j;
                zxr[row * DTOT + col] = acc[fm][fn][j];
            }
        }
}

// ---------------------------------------------------------------------------
// prep: RMS-norm Br/Cr; alpha/beta/gamma packed as float4 in (b,h,l) layout.
// ---------------------------------------------------------------------------
__global__ __launch_bounds__(64) void prep_kernel(const float* __restrict__ zx,
        const float* __restrict__ dt_bias, const float* __restrict__ A_log,
        const float* __restrict__ B_norm_w, const float* __restrict__ C_norm_w,
        float* __restrict__ Bg, float* __restrict__ Cg,
        float4* __restrict__ abg4) {
    const int bl = blockIdx.x;
    const int b = bl >> 10, l = bl & (LSEQ - 1);
    const int t  = threadIdx.x;
    const float* row = zx + (size_t)bl * DTOT;
    const float br = row[OFF_BR + t];
    const float cr = row[OFF_CR + t];
    float ssb = br * br, ssc = cr * cr;
    #pragma unroll
    for (int k = 1; k < 64; k <<= 1) { ssb += __shfl_xor(ssb, k); ssc += __shfl_xor(ssc, k); }
    const float scB = rsqrtf(ssb * (1.f / 64.f) + 1e-5f);
    const float scC = rsqrtf(ssc * (1.f / 64.f) + 1e-5f);
    Bg[(size_t)bl * 64 + t] = br * scB * B_norm_w[t];
    Cg[(size_t)bl * 64 + t] = cr * scC * C_norm_w[t];
    if (t < NH) {
        const float dtr = row[OFF_DT + t] + dt_bias[t];
        const float dt  = (dtr > 20.f) ? dtr : log1pf(expf(dtr));
        const float lamr = row[OFF_LAM + t];
        const float lam  = 1.f / (1.f + expf(-lamr));
        const float Ah   = -expf(A_log[t]);
        const float al   = expf(dt * Ah);
        const size_t o = ((size_t)b * NH + t) * LSEQ + l;
        abg4[o] = make_float4(al, (1.f - lam) * dt * al, lam * dt, 0.f);
    }
}

// ---------------------------------------------------------------------------
// cumsum of thr over L, per (b,h): 32 dims.
// ---------------------------------------------------------------------------
__global__ __launch_bounds__(256) void cumsum_kernel(const float* __restrict__ zx,
                                                     float* __restrict__ th_cs) {
    const int bh = blockIdx.x;
    const int b = bh >> 5, h = bh & 31;
    const int d = threadIdx.x & 31, seg = threadIdx.x >> 5;
    const float* base = zx + (size_t)b * LSEQ * DTOT + OFF_TH + h * 32 + d;
    float* out = th_cs + (size_t)b * LSEQ * 1024 + h * 32 + d;
    __shared__ float sums[8][33];
    const int l0 = seg * 128;
    float s = 0.f;
    #pragma unroll 4
    for (int i = 0; i < 128; ++i) s += base[(size_t)(l0 + i) * DTOT];
    sums[seg][d] = s;
    __syncthreads();
    float acc = 0.f;
    for (int s2 = 0; s2 < seg; ++s2) acc += sums[s2][d];
    #pragma unroll 4
    for (int i = 0; i < 128; ++i) {
        acc += base[(size_t)(l0 + i) * DTOT];
        out[(size_t)(l0 + i) * 1024] = acc;
    }
}

// ---------------------------------------------------------------------------
// rot: Bh/Ch = rot(broadcast(Bg/Cg)+bias). Brot/Crot layout (B,NH,L,DS).
// ---------------------------------------------------------------------------
__global__ __launch_bounds__(256) void rot_kernel(const float* __restrict__ th_cs,
        const float* __restrict__ Bg, const float* __restrict__ Cg,
        const float* __restrict__ B_bias, const float* __restrict__ C_bias,
        float* __restrict__ Brot, float* __restrict__ Crot) {
    const size_t idx = (size_t)blockIdx.x * 256 + threadIdx.x;
    const int j = (int)(idx & 31);
    const int h = (int)((idx >> 5) & 31);
    const size_t bl = idx >> 10;
    const int l = (int)(bl & (LSEQ - 1));
    const int b = (int)(bl >> 10);
    const float th = th_cs[idx];
    float s, c;
    sincosf(th, &s, &c);
    float v1 = Bg[bl * 64 + j]      + B_bias[h * 64 + j];
    float v2 = Bg[bl * 64 + 32 + j] + B_bias[h * 64 + 32 + j];
    const size_t ob = ((size_t)(b * NH + h) * LSEQ + l) * DS + j;
    Brot[ob]      = v1 * c - v2 * s;
    Brot[ob + 32] = v1 * s + v2 * c;
    v1 = Cg[bl * 64 + j]      + C_bias[h * 64 + j];
    v2 = Cg[bl * 64 + 32 + j] + C_bias[h * 64 + 32 + j];
    Crot[ob]      = v1 * c - v2 * s;
    Crot[ob + 32] = v1 * s + v2 * c;
}

// ---------------------------------------------------------------------------
// DPP 16-lane row sum (VALU pipe). Lane 15 of each 16-lane row holds the sum.
// ---------------------------------------------------------------------------
__device__ __forceinline__ float row_sum16(float x) {
    int t;
    t = __builtin_amdgcn_update_dpp(0, __float_as_int(x), 0x111, 0xf, 0xf, true);
    x += __int_as_float(t);
    t = __builtin_amdgcn_update_dpp(0, __float_as_int(x), 0x112, 0xf, 0xf, true);
    x += __int_as_float(t);
    t = __builtin_amdgcn_update_dpp(0, __float_as_int(x), 0x114, 0xf, 0xf, true);
    x += __int_as_float(t);
    t = __builtin_amdgcn_update_dpp(0, __float_as_int(x), 0x118, 0xf, 0xf, true);
    x += __int_as_float(t);
    return x;
}

// ---------------------------------------------------------------------------
// scan v3: NO LDS, no barriers. DEPTH-8 rotating register pipeline straight
// from global (B/C/x/abg are L2/L3-resident — rot/prep just wrote them).
// At step t: compute from regs[d], then issue loads for step t+DEPTH into
// regs[d]. Full unroll keeps all indices compile-time (regs, not scratch).
// ---------------------------------------------------------------------------
#define DEPTH 8

__global__ __launch_bounds__(256) void scan_kernel(const float* __restrict__ zx,
        const float* __restrict__ Brot, const float* __restrict__ Crot,
        const float4* __restrict__ abg4, const float* __restrict__ Dp,
        float* __restrict__ yb) {
    const int blk = blockIdx.x;
    const int ptile = blk & 3, h = (blk >> 2) & 31, b = blk >> 7;
    const int tid = threadIdx.x;
    const int pl = tid >> 4, ng = tid & 15;
    const int p = ptile * 16 + pl;
    const int n0 = ng * 4;

    const size_t bh = (size_t)b * NH + h;
    const float* Bbase = Brot + bh * LSEQ * DS + n0;
    const float* Cbase = Crot + bh * LSEQ * DS + n0;
    const float4* abase = abg4 + bh * LSEQ;
    const float* xbase = zx + (size_t)b * LSEQ * DTOT + OFF_X + h * HD + p;
    const float Dh = Dp[h];
    float* ybase = yb + (size_t)b * LSEQ * DIN + h * HD + p;

    float4 Bb[DEPTH], Cb[DEPTH], ab[DEPTH];
    float  xb[DEPTH];

    #pragma unroll
    for (int d = 0; d < DEPTH; ++d) {
        Bb[d] = *(const float4*)(Bbase + (size_t)d * DS);
        Cb[d] = *(const float4*)(Cbase + (size_t)d * DS);
        ab[d] = ((const float4*)abase)[d];
        xb[d] = xbase[(size_t)d * DTOT];
    }

    float hs0 = 0.f, hs1 = 0.f, hs2 = 0.f, hs3 = 0.f;
    float Bp0 = 0.f, Bp1 = 0.f, Bp2 = 0.f, Bp3 = 0.f;
    float xprev = 0.f;

    for (int t0 = 0; t0 < LSEQ; t0 += DEPTH) {
        #pragma unroll
        for (int d = 0; d < DEPTH; ++d) {
            const float4 Bv = Bb[d];
            const float4 Cv = Cb[d];
            const float4 av = ab[d];
            const float  xv = xb[d];
            // issue loads for step t0+d+DEPTH (clamped at tail; redundant loads harmless)
            int tn = t0 + d + DEPTH; if (tn > LSEQ - 1) tn = LSEQ - 1;
            Bb[d] = *(const float4*)(Bbase + (size_t)tn * DS);
            Cb[d] = *(const float4*)(Cbase + (size_t)tn * DS);
            ab[d] = ((const float4*)abase)[tn];
            xb[d] = xbase[(size_t)tn * DTOT];
            // compute step t0+d
            const float cp = av.y * xprev;
            const float cc = av.z * xv;
            float ys;
            hs0 = fmaf(av.x, hs0, fmaf(cp, Bp0, cc * Bv.x)); ys  = Cv.x * hs0;
            hs1 = fmaf(av.x, hs1, fmaf(cp, Bp1, cc * Bv.y)); ys += Cv.y * hs1;
            hs2 = fmaf(av.x, hs2, fmaf(cp, Bp2, cc * Bv.z)); ys += Cv.z * hs2;
            hs3 = fmaf(av.x, hs3, fmaf(cp, Bp3, cc * Bv.w)); ys += Cv.w * hs3;
            ys = row_sum16(ys);
            if (ng == 15) ybase[(size_t)(t0 + d) * DIN] = fmaf(Dh, xv, ys);
            Bp0 = Bv.x; Bp1 = Bv.y; Bp2 = Bv.z; Bp3 = Bv.w;
            xprev = xv;
        }
    }
}

// ---------------------------------------------------------------------------
// gate + final RMS norm
// ---------------------------------------------------------------------------
__global__ __launch_bounds__(256) void gate_norm_kernel(const float* __restrict__ yb,
        const float* __restrict__ zx, const float* __restrict__ norm_w,
        float* __restrict__ gn) {
    const int bl = blockIdx.x;
    const int tid = threadIdx.x;
    const float* yrow = yb + (size_t)bl * DIN;
    const float* zrow = zx + (size_t)bl * DTOT + OFF_Z;
    float g[8];
    float ss = 0.f;
    #pragma unroll
    for (int i = 0; i < 8; ++i) {
        const int c = tid + i * 256;
        const float yv = yrow[c];
        const float zv = zrow[c];
        const float sg = 1.f / (1.f + expf(-zv));
        const float gv = yv * zv * sg;
        g[i] = gv;
        ss += gv * gv;
    }
    #pragma unroll
    for (int k = 1; k < 64; k <<= 1) ss += __shfl_xor(ss, k);
    __shared__ float wsum[4];
    if ((tid & 63) == 0) wsum[tid >> 6] = ss;
    __syncthreads();
    ss = wsum[0] + wsum[1] + wsum[2] + wsum[3];
    const float sc = rsqrtf(ss * (1.f / 2048.f) + 1e-5f);
    #pragma unroll
    for (int i = 0; i < 8; ++i) {
        const int c = tid + i * 256;
        gn[(size_t)bl * DIN + c] = g[i] * sc * norm_w[c];
    }
}

// ---------------------------------------------------------------------------
extern "C" void kernel_launch(void* const* d_in, const int* in_sizes, int n_in,
                              void* d_out, int out_size, void* d_ws, size_t ws_size,
                              hipStream_t stream) {
    const float* u          = (const float*)d_in[0];
    const float* in_proj_w  = (const float*)d_in[1];
    const float* dt_bias    = (const float*)d_in[2];
    const float* A_log      = (const float*)d_in[3];
    const float* Dp         = (const float*)d_in[4];
    const float* B_norm_w   = (const float*)d_in[5];
    const float* C_norm_w   = (const float*)d_in[6];
    const float* B_bias     = (const float*)d_in[7];
    const float* C_bias     = (const float*)d_in[8];
    const float* norm_w     = (const float*)d_in[9];
    const float* out_proj_w = (const float*)d_in[10];
    float* out = (float*)d_out;

    float* p = (float*)d_ws;
    float* zx    = p; p += (size_t)ROWS * DTOT;
    float* th_cs = p; p += (size_t)ROWS * 1024;
    float* Brot  = p; p += (size_t)ROWS * 2048;
    float* Crot  = p; p += (size_t)ROWS * 2048;
    float* Bg    = p; p += (size_t)ROWS * 64;
    float* Cg    = p; p += (size_t)ROWS * 64;
    float4* abg4 = (float4*)p; p += (size_t)ROWS * NH * 4;
    float* yb    = p; p += (size_t)ROWS * 2048;
    float* gn    = Brot;   // reuse: Brot dead after scan

    // 1a. z/x block via bf16 MFMA: zx[:, 0:4096]
    mfma_gemm_zx<<<dim3(NZX / 128, ROWS / 128), 256, 0, stream>>>(u, in_proj_w, zx);
    // 1b. sensitive columns via split-bf16 3-pass MFMA: zx[:, 4096:5312]
    mfma_gemm_rem3<<<dim3(NREM / 64, ROWS / 128), 256, 0, stream>>>(
        u, in_proj_w + (size_t)NZX * DMODEL, zx + NZX);
    // 2. per-row prep
    prep_kernel<<<ROWS, 64, 0, stream>>>(zx, dt_bias, A_log, B_norm_w, C_norm_w,
                                         Bg, Cg, abg4);
    // 3. cumsum of theta over L
    cumsum_kernel<<<BB * NH, 256, 0, stream>>>(zx, th_cs);
    // 4. rotary on B/C
    rot_kernel<<<(ROWS * 1024) / 256, 256, 0, stream>>>(th_cs, Bg, Cg, B_bias, C_bias,
                                                        Brot, Crot);
    // 5. sequential scan over L (register-pipelined, no LDS)
    scan_kernel<<<BB * NH * 4, 256, 0, stream>>>(zx, Brot, Crot, abg4, Dp, yb);
    // 6. gate + RMS norm
    gate_norm_kernel<<<ROWS, 256, 0, stream>>>(yb, zx, norm_w, gn);
    // 7. out = gn @ out_proj_w^T  via bf16 MFMA (128x64 tile, 256 blocks)
    mfma_gemm_out<<<dim3(DMODEL / 64, ROWS / 128), 256, 0, stream>>>(
        gn, out_proj_w, out, DIN, DMODEL);
}